// Round 1
// baseline (202.734 us; speedup 1.0000x reference)
//
#include <hip/hip_runtime.h>
#include <stdint.h>

#define B_ 2
#define T_ 2048
#define C_ 1024
#define H_ 16
#define D_ 64
#define SCALE_ 0.125f

typedef unsigned short ushort_t;
typedef __attribute__((ext_vector_type(8))) __bf16 bf16x8;
typedef __attribute__((ext_vector_type(4))) float f32x4;
typedef __attribute__((ext_vector_type(4))) unsigned short ushort4_t;

__device__ __forceinline__ float bf2f(ushort_t u) {
    union { unsigned int u; float f; } v; v.u = ((unsigned int)u) << 16; return v.f;
}
__device__ __forceinline__ ushort_t f2bf(float f) {
    union { float f; unsigned int u; } v; v.f = f;
    unsigned int r = v.u + 0x7FFFu + ((v.u >> 16) & 1u);
    return (ushort_t)(r >> 16);
}

__device__ __forceinline__ void gl16(const void* g, void* l) {
    __builtin_amdgcn_global_load_lds(
        (const __attribute__((address_space(1))) void*)g,
        (__attribute__((address_space(3))) void*)l, 16, 0, 0);
}

__device__ __forceinline__ f32x4 mfma16(bf16x8 a, bf16x8 b, f32x4 c) {
    return __builtin_amdgcn_mfma_f32_16x16x32_bf16(a, b, c, 0, 0, 0);
}

// ---------------- fp32 -> bf16 convert ----------------
__global__ __launch_bounds__(256) void cvt_kernel(const float* __restrict__ in,
                                                  ushort_t* __restrict__ out, int n) {
    int stride = gridDim.x * blockDim.x;
    for (int i = blockIdx.x * blockDim.x + threadIdx.x; i * 4 < n; i += stride) {
        float4 v = *(const float4*)(in + (size_t)i * 4);
        ushort4_t o;
        o.x = f2bf(v.x); o.y = f2bf(v.y); o.z = f2bf(v.z); o.w = f2bf(v.w);
        *(ushort4_t*)(out + (size_t)i * 4) = o;
    }
}

// ---------------- GEMM: C[M,N] = A[M,K] * B[N,K]^T + bias ----------------
// A, B bf16 row-major (B stored [N][K] i.e. already transposed = weight layout).
template <int BF16OUT>
__global__ __launch_bounds__(256) void gemm_bt(const ushort_t* __restrict__ A,
                                               const ushort_t* __restrict__ Bw,
                                               const float* __restrict__ bias,
                                               ushort_t* __restrict__ outb,
                                               float* __restrict__ outf,
                                               int M, int N, int K) {
    __shared__ ushort_t As[128 * 32];
    __shared__ ushort_t Bs[128 * 32];
    int tid = threadIdx.x, w = tid >> 6, lane = tid & 63;
    int lr = lane >> 4, lc = lane & 15;
    int wr = w >> 1, wc = w & 1;
    int row0 = blockIdx.y * 128, col0 = blockIdx.x * 128;

    f32x4 acc[4][4];
#pragma unroll
    for (int mf = 0; mf < 4; ++mf)
#pragma unroll
        for (int nf = 0; nf < 4; ++nf) acc[mf][nf] = (f32x4){0.f, 0.f, 0.f, 0.f};

    for (int k0 = 0; k0 < K; k0 += 32) {
#pragma unroll
        for (int j = 0; j < 2; ++j) {
            int idx = j * 256 + tid;
            int r = idx >> 2, c = (idx & 3) * 8;
            gl16(A + (size_t)(row0 + r) * K + k0 + c, &As[idx * 8]);
            gl16(Bw + (size_t)(col0 + r) * K + k0 + c, &Bs[idx * 8]);
        }
        __syncthreads();
        bf16x8 af[4], bfr[4];
#pragma unroll
        for (int mf = 0; mf < 4; ++mf)
            af[mf] = *(const bf16x8*)&As[(wr * 64 + mf * 16 + lc) * 32 + 8 * lr];
#pragma unroll
        for (int nf = 0; nf < 4; ++nf)
            bfr[nf] = *(const bf16x8*)&Bs[(wc * 64 + nf * 16 + lc) * 32 + 8 * lr];
#pragma unroll
        for (int mf = 0; mf < 4; ++mf)
#pragma unroll
            for (int nf = 0; nf < 4; ++nf)
                acc[mf][nf] = mfma16(af[mf], bfr[nf], acc[mf][nf]);
        __syncthreads();
    }
    // epilogue: C/D layout col=lane&15, row=4*(lane>>4)+reg
#pragma unroll
    for (int mf = 0; mf < 4; ++mf)
#pragma unroll
        for (int nf = 0; nf < 4; ++nf) {
            int col = col0 + wc * 64 + nf * 16 + lc;
            float bv = bias[col];
#pragma unroll
            for (int r = 0; r < 4; ++r) {
                int row = row0 + wr * 64 + mf * 16 + 4 * lr + r;
                float v = acc[mf][nf][r] + bv;
                if (BF16OUT)
                    outb[(size_t)row * N + col] = f2bf(v);
                else
                    outf[(size_t)row * N + col] = v;
            }
        }
}

// ---------------- RoPE + scatter to [B,H,T,D] (Q,K) and [B,H,D,T] (V) ----------------
__global__ __launch_bounds__(256) void rope_scatter(const ushort_t* __restrict__ qkv,
                                                    const float* __restrict__ cosT,
                                                    const float* __restrict__ sinT,
                                                    ushort_t* __restrict__ Qr,
                                                    ushort_t* __restrict__ Kr,
                                                    ushort_t* __restrict__ Vt) {
    int blk = blockIdx.x;
    int tt = blk & 31;
    int h = (blk >> 5) & 15;
    int b = blk >> 9;
    int t0 = tt * 64;
    int bh = b * H_ + h;

    // Q/K rope: 64 t x 32 d2 = 2048 items
#pragma unroll
    for (int it = 0; it < 8; ++it) {
        int idx = it * 256 + threadIdx.x;
        int tl = idx >> 5;
        int d2 = idx & 31;
        int t = t0 + tl;
        float c = cosT[t * 32 + d2], s = sinT[t * 32 + d2];
        const ushort_t* row = &qkv[(size_t)(b * T_ + t) * 3072 + h * 64];
        float q1 = bf2f(row[2 * d2]), q2 = bf2f(row[2 * d2 + 1]);
        float k1 = bf2f(row[1024 + 2 * d2]), k2 = bf2f(row[1024 + 2 * d2 + 1]);
        size_t obase = ((size_t)bh * T_ + t) * D_;
        Qr[obase + d2] = f2bf(q1 * c - q2 * s);
        Qr[obase + d2 + 32] = f2bf(q1 * s + q2 * c);
        Kr[obase + d2] = f2bf(k1 * c - k2 * s);
        Kr[obase + d2 + 32] = f2bf(k1 * s + k2 * c);
    }
    // V transpose through LDS
    __shared__ ushort_t vtile[64 * 64];
#pragma unroll
    for (int it = 0; it < 16; ++it) {
        int idx = it * 256 + threadIdx.x;
        int tl = idx >> 6, d = idx & 63;
        vtile[tl * 64 + d] = qkv[(size_t)(b * T_ + t0 + tl) * 3072 + 2048 + h * 64 + d];
    }
    __syncthreads();
#pragma unroll
    for (int it = 0; it < 16; ++it) {
        int idx = it * 256 + threadIdx.x;
        int d = idx >> 6, tl = idx & 63;
        Vt[((size_t)bh * D_ + d) * T_ + t0 + tl] = vtile[tl * 64 + d];
    }
}

// ---------------- causal flash attention ----------------
// grid: (B*H) * (T/64); block 256 (4 waves x 16 q-rows)
__global__ __launch_bounds__(256) void attn_kernel(const ushort_t* __restrict__ Qr,
                                                   const ushort_t* __restrict__ Kr,
                                                   const ushort_t* __restrict__ Vt,
                                                   ushort_t* __restrict__ attnb) {
    int blk = blockIdx.x;
    int qt = blk & 31;
    int bh = blk >> 5;
    int b = bh >> 4, h = bh & 15;
    const ushort_t* Qp = Qr + (size_t)bh * T_ * D_;
    const ushort_t* Kp = Kr + (size_t)bh * T_ * D_;
    const ushort_t* Vp = Vt + (size_t)bh * D_ * T_;
    int tid = threadIdx.x, w = tid >> 6, lane = tid & 63;
    int lr = lane >> 4, lc = lane & 15;

    __shared__ ushort_t Ks[64 * 64];
    __shared__ ushort_t Vs[64 * 64];
    __shared__ ushort_t Ps[4][16 * 64];

    int qrow = qt * 64 + w * 16 + lc;
    bf16x8 qf0 = *(const bf16x8*)(Qp + (size_t)qrow * D_ + 8 * lr);
    bf16x8 qf1 = *(const bf16x8*)(Qp + (size_t)qrow * D_ + 32 + 8 * lr);

    float m_st[4], l_st[4];
    f32x4 acc[4];
#pragma unroll
    for (int r = 0; r < 4; ++r) { m_st[r] = -1e30f; l_st[r] = 0.f; }
#pragma unroll
    for (int f = 0; f < 4; ++f) acc[f] = (f32x4){0.f, 0.f, 0.f, 0.f};

    int qg = qt * 64 + w * 16 + 4 * lr;  // + r gives global q row

    for (int kt = 0; kt <= qt; ++kt) {
        int t0 = kt * 64;
        // stage K[t0..t0+63][0..64) and V^T[0..64)[t0..t0+63], XOR-swizzled via source
#pragma unroll
        for (int j = 0; j < 2; ++j) {
            int idx = j * 256 + tid;
            int row = idx >> 3, ch = idx & 7;
            int sch = ch ^ (row & 7);
            gl16(Kp + (size_t)(t0 + row) * D_ + sch * 8, &Ks[idx * 8]);
            gl16(Vp + (size_t)row * T_ + t0 + sch * 8, &Vs[idx * 8]);
        }
        __syncthreads();

        // S = Q K^T  (4 col-frags x 2 k-steps)
        f32x4 s[4];
#pragma unroll
        for (int f = 0; f < 4; ++f) {
            s[f] = (f32x4){0.f, 0.f, 0.f, 0.f};
            int row = 16 * f + lc;
#pragma unroll
            for (int kk = 0; kk < 2; ++kk) {
                bf16x8 kf = *(const bf16x8*)&Ks[row * 64 + (((lr + 4 * kk) ^ (row & 7)) * 8)];
                s[f] = mfma16(kk ? qf1 : qf0, kf, s[f]);
            }
        }
        // scale + causal mask + tile row-max
        float tmax[4] = {-1e30f, -1e30f, -1e30f, -1e30f};
#pragma unroll
        for (int f = 0; f < 4; ++f) {
            int kcol = t0 + 16 * f + lc;
#pragma unroll
            for (int r = 0; r < 4; ++r) {
                float v = s[f][r] * SCALE_;
                v = (kcol > qg + r) ? -1e30f : v;
                s[f][r] = v;
                tmax[r] = fmaxf(tmax[r], v);
            }
        }
#pragma unroll
        for (int off = 1; off < 16; off <<= 1)
#pragma unroll
            for (int r = 0; r < 4; ++r)
                tmax[r] = fmaxf(tmax[r], __shfl_xor(tmax[r], off, 64));

        float alpha[4], psum[4];
#pragma unroll
        for (int r = 0; r < 4; ++r) {
            float mn = fmaxf(m_st[r], tmax[r]);
            alpha[r] = __expf(m_st[r] - mn);
            m_st[r] = mn;
            psum[r] = 0.f;
        }
#pragma unroll
        for (int f = 0; f < 4; ++f)
#pragma unroll
            for (int r = 0; r < 4; ++r) {
                float p = __expf(s[f][r] - m_st[r]);
                s[f][r] = p;
                psum[r] += p;
            }
#pragma unroll
        for (int off = 1; off < 16; off <<= 1)
#pragma unroll
            for (int r = 0; r < 4; ++r) psum[r] += __shfl_xor(psum[r], off, 64);
#pragma unroll
        for (int r = 0; r < 4; ++r) l_st[r] = l_st[r] * alpha[r] + psum[r];
#pragma unroll
        for (int f = 0; f < 4; ++f)
#pragma unroll
            for (int r = 0; r < 4; ++r) acc[f][r] *= alpha[r];

        // write P (bf16) to per-wave LDS, swizzled
#pragma unroll
        for (int f = 0; f < 4; ++f)
#pragma unroll
            for (int r = 0; r < 4; ++r) {
                int prow = 4 * lr + r, pcol = 16 * f + lc;
                Ps[w][prow * 64 + (((pcol >> 3) ^ (prow & 7)) * 8) + (pcol & 7)] = f2bf(s[f][r]);
            }
        // PV: same-wave LDS write->read, compiler orders via lgkmcnt
#pragma unroll
        for (int kk = 0; kk < 2; ++kk) {
            bf16x8 pf = *(const bf16x8*)&Ps[w][lc * 64 + (((lr + 4 * kk) ^ (lc & 7)) * 8)];
#pragma unroll
            for (int f = 0; f < 4; ++f) {
                int vrow = 16 * f + lc;
                bf16x8 vfr = *(const bf16x8*)&Vs[vrow * 64 + (((lr + 4 * kk) ^ (vrow & 7)) * 8)];
                acc[f] = mfma16(pf, vfr, acc[f]);
            }
        }
        __syncthreads();
    }
    // normalize + store to attn buffer [B*T, H*D] bf16
#pragma unroll
    for (int r = 0; r < 4; ++r) l_st[r] = 1.f / l_st[r];
#pragma unroll
    for (int f = 0; f < 4; ++f)
#pragma unroll
        for (int r = 0; r < 4; ++r) {
            int t = qt * 64 + w * 16 + 4 * lr + r;
            attnb[((size_t)(b * T_ + t)) * 1024 + h * 64 + 16 * f + lc] = f2bf(acc[f][r] * l_st[r]);
        }
}

extern "C" void kernel_launch(void* const* d_in, const int* in_sizes, int n_in,
                              void* d_out, int out_size, void* d_ws, size_t ws_size,
                              hipStream_t stream) {
    const float* hs     = (const float*)d_in[0];
    const float* cosp   = (const float*)d_in[1];
    const float* sinp   = (const float*)d_in[2];
    const float* qkv_w  = (const float*)d_in[3];
    const float* qkv_b  = (const float*)d_in[4];
    const float* proj_w = (const float*)d_in[5];
    const float* proj_b = (const float*)d_in[6];
    float* out = (float*)d_out;

    const int M = B_ * T_;            // 4096
    ushort_t* Xb     = (ushort_t*)d_ws;                    // 4096*1024
    ushort_t* Wqkvb  = Xb + (size_t)M * C_;                // 3072*1024
    ushort_t* Wprojb = Wqkvb + (size_t)3072 * C_;          // 1024*1024
    ushort_t* QKV    = Wprojb + (size_t)C_ * C_;           // 4096*3072
    ushort_t* Qr     = QKV + (size_t)M * 3072;             // 2*16*2048*64
    ushort_t* Kr     = Qr + (size_t)B_ * H_ * T_ * D_;
    ushort_t* Vt     = Kr + (size_t)B_ * H_ * T_ * D_;
    ushort_t* attnb  = Vt + (size_t)B_ * H_ * T_ * D_;     // 4096*1024

    cvt_kernel<<<1024, 256, 0, stream>>>(hs, Xb, M * C_);
    cvt_kernel<<<1024, 256, 0, stream>>>(qkv_w, Wqkvb, 3072 * C_);
    cvt_kernel<<<256, 256, 0, stream>>>(proj_w, Wprojb, C_ * C_);

    gemm_bt<1><<<dim3(3072 / 128, M / 128), 256, 0, stream>>>(
        Xb, Wqkvb, qkv_b, QKV, nullptr, M, 3072, C_);

    rope_scatter<<<B_ * H_ * (T_ / 64), 256, 0, stream>>>(QKV, cosp, sinp, Qr, Kr, Vt);

    attn_kernel<<<B_ * H_ * (T_ / 64), 256, 0, stream>>>(Qr, Kr, Vt, attnb);

    gemm_bt<0><<<dim3(1024 / 128, M / 128), 256, 0, stream>>>(
        attnb, Wprojb, proj_b, nullptr, out, M, C_, C_);
}

// Round 2
// 175.712 us; speedup vs baseline: 1.1538x; 1.1538x over previous
//
#include <hip/hip_runtime.h>
#include <stdint.h>

#define B_ 2
#define T_ 2048
#define C_ 1024
#define H_ 16
#define D_ 64
// SCALE * log2(e): softmax computed in exp2 domain
#define SCALE_L2E 0.1803368801111244f

typedef unsigned short ushort_t;
typedef __attribute__((ext_vector_type(8))) __bf16 bf16x8;
typedef __attribute__((ext_vector_type(4))) float f32x4;
typedef __attribute__((ext_vector_type(4))) unsigned short ushort4_t;

__device__ __forceinline__ float bf2f(ushort_t u) {
    union { unsigned int u; float f; } v; v.u = ((unsigned int)u) << 16; return v.f;
}
__device__ __forceinline__ ushort_t f2bf(float f) {
    union { float f; unsigned int u; } v; v.f = f;
    unsigned int r = v.u + 0x7FFFu + ((v.u >> 16) & 1u);
    return (ushort_t)(r >> 16);
}

__device__ __forceinline__ void gl16(const void* g, void* l) {
    __builtin_amdgcn_global_load_lds(
        (const __attribute__((address_space(1))) void*)g,
        (__attribute__((address_space(3))) void*)l, 16, 0, 0);
}

__device__ __forceinline__ f32x4 mfma16(bf16x8 a, bf16x8 b, f32x4 c) {
    return __builtin_amdgcn_mfma_f32_16x16x32_bf16(a, b, c, 0, 0, 0);
}

// ---------------- fp32 -> bf16 convert ----------------
__global__ __launch_bounds__(256) void cvt_kernel(const float* __restrict__ in,
                                                  ushort_t* __restrict__ out, int n) {
    int stride = gridDim.x * blockDim.x;
    for (int i = blockIdx.x * blockDim.x + threadIdx.x; i * 4 < n; i += stride) {
        float4 v = *(const float4*)(in + (size_t)i * 4);
        ushort4_t o;
        o.x = f2bf(v.x); o.y = f2bf(v.y); o.z = f2bf(v.z); o.w = f2bf(v.w);
        *(ushort4_t*)(out + (size_t)i * 4) = o;
    }
}

// ---------------- GEMM: C[M,N] = A[M,K] * B[N,K]^T + bias ----------------
template <int BF16OUT>
__global__ __launch_bounds__(256) void gemm_bt(const ushort_t* __restrict__ A,
                                               const ushort_t* __restrict__ Bw,
                                               const float* __restrict__ bias,
                                               ushort_t* __restrict__ outb,
                                               float* __restrict__ outf,
                                               int M, int N, int K) {
    __shared__ ushort_t As[128 * 32];
    __shared__ ushort_t Bs[128 * 32];
    int tid = threadIdx.x, w = tid >> 6, lane = tid & 63;
    int lr = lane >> 4, lc = lane & 15;
    int wr = w >> 1, wc = w & 1;
    int row0 = blockIdx.y * 128, col0 = blockIdx.x * 128;

    f32x4 acc[4][4];
#pragma unroll
    for (int mf = 0; mf < 4; ++mf)
#pragma unroll
        for (int nf = 0; nf < 4; ++nf) acc[mf][nf] = (f32x4){0.f, 0.f, 0.f, 0.f};

    for (int k0 = 0; k0 < K; k0 += 32) {
#pragma unroll
        for (int j = 0; j < 2; ++j) {
            int idx = j * 256 + tid;
            int r = idx >> 2, c = (idx & 3) * 8;
            gl16(A + (size_t)(row0 + r) * K + k0 + c, &As[idx * 8]);
            gl16(Bw + (size_t)(col0 + r) * K + k0 + c, &Bs[idx * 8]);
        }
        __syncthreads();
        bf16x8 af[4], bfr[4];
#pragma unroll
        for (int mf = 0; mf < 4; ++mf)
            af[mf] = *(const bf16x8*)&As[(wr * 64 + mf * 16 + lc) * 32 + 8 * lr];
#pragma unroll
        for (int nf = 0; nf < 4; ++nf)
            bfr[nf] = *(const bf16x8*)&Bs[(wc * 64 + nf * 16 + lc) * 32 + 8 * lr];
#pragma unroll
        for (int mf = 0; mf < 4; ++mf)
#pragma unroll
            for (int nf = 0; nf < 4; ++nf)
                acc[mf][nf] = mfma16(af[mf], bfr[nf], acc[mf][nf]);
        __syncthreads();
    }
#pragma unroll
    for (int mf = 0; mf < 4; ++mf)
#pragma unroll
        for (int nf = 0; nf < 4; ++nf) {
            int col = col0 + wc * 64 + nf * 16 + lc;
            float bv = bias[col];
#pragma unroll
            for (int r = 0; r < 4; ++r) {
                int row = row0 + wr * 64 + mf * 16 + 4 * lr + r;
                float v = acc[mf][nf][r] + bv;
                if (BF16OUT)
                    outb[(size_t)row * N + col] = f2bf(v);
                else
                    outf[(size_t)row * N + col] = v;
            }
        }
}

// ---------------- RoPE + scatter to [B,H,T,D] (Q,K) and [B,H,D,T] (V) ----------------
__global__ __launch_bounds__(256) void rope_scatter(const ushort_t* __restrict__ qkv,
                                                    const float* __restrict__ cosT,
                                                    const float* __restrict__ sinT,
                                                    ushort_t* __restrict__ Qr,
                                                    ushort_t* __restrict__ Kr,
                                                    ushort_t* __restrict__ Vt) {
    int blk = blockIdx.x;
    int tt = blk & 31;
    int h = (blk >> 5) & 15;
    int b = blk >> 9;
    int t0 = tt * 64;
    int bh = b * H_ + h;

#pragma unroll
    for (int it = 0; it < 8; ++it) {
        int idx = it * 256 + threadIdx.x;
        int tl = idx >> 5;
        int d2 = idx & 31;
        int t = t0 + tl;
        float c = cosT[t * 32 + d2], s = sinT[t * 32 + d2];
        const ushort_t* row = &qkv[(size_t)(b * T_ + t) * 3072 + h * 64];
        float q1 = bf2f(row[2 * d2]), q2 = bf2f(row[2 * d2 + 1]);
        float k1 = bf2f(row[1024 + 2 * d2]), k2 = bf2f(row[1024 + 2 * d2 + 1]);
        size_t obase = ((size_t)bh * T_ + t) * D_;
        Qr[obase + d2] = f2bf(q1 * c - q2 * s);
        Qr[obase + d2 + 32] = f2bf(q1 * s + q2 * c);
        Kr[obase + d2] = f2bf(k1 * c - k2 * s);
        Kr[obase + d2 + 32] = f2bf(k1 * s + k2 * c);
    }
    __shared__ ushort_t vtile[64 * 64];
#pragma unroll
    for (int it = 0; it < 16; ++it) {
        int idx = it * 256 + threadIdx.x;
        int tl = idx >> 6, d = idx & 63;
        vtile[tl * 64 + d] = qkv[(size_t)(b * T_ + t0 + tl) * 3072 + 2048 + h * 64 + d];
    }
    __syncthreads();
#pragma unroll
    for (int it = 0; it < 16; ++it) {
        int idx = it * 256 + threadIdx.x;
        int d = idx >> 6, tl = idx & 63;
        Vt[((size_t)bh * D_ + d) * T_ + t0 + tl] = vtile[tl * 64 + d];
    }
}

// ---------------- causal flash attention, 2-phase double-buffered ----------------
// grid: 1024 blocks; per-CU-balanced (bh,qt) remap so every stride-256 group
// of 4 blocks sums to 66 tile-iters.
__global__ __launch_bounds__(256) void attn_kernel(const ushort_t* __restrict__ Qr,
                                                   const ushort_t* __restrict__ Kr,
                                                   const ushort_t* __restrict__ Vt,
                                                   ushort_t* __restrict__ attnb) {
    int blk = blockIdx.x;
    int g = blk >> 8;          // 0..3
    int r_ = blk & 255;
    int a = r_ & 31;
    int u = r_ >> 5;           // 0..7
    int bh = u * 4 + g;        // 0..31
    int qt;
    if (g == 0) qt = a;
    else if (g == 1) qt = 31 - a;
    else if (g == 2) qt = 31 - ((a + 16) & 31);
    else qt = (a + 16) & 31;
    int b = bh >> 4, h = bh & 15;

    const ushort_t* Qp = Qr + (size_t)bh * T_ * D_;
    const ushort_t* Kp = Kr + (size_t)bh * T_ * D_;
    const ushort_t* Vp = Vt + (size_t)bh * D_ * T_;
    int tid = threadIdx.x, w = tid >> 6, lane = tid & 63;
    int lr = lane >> 4, lc = lane & 15;

    __shared__ ushort_t Ks[2][64 * 64];
    __shared__ ushort_t Vs[2][64 * 64];
    __shared__ ushort_t Ps[4][16 * 64];

    int qrow = qt * 64 + w * 16 + lc;
    bf16x8 qf0 = *(const bf16x8*)(Qp + (size_t)qrow * D_ + 8 * lr);
    bf16x8 qf1 = *(const bf16x8*)(Qp + (size_t)qrow * D_ + 32 + 8 * lr);

    float m_st[4], l_st[4];
    f32x4 acc[4];
#pragma unroll
    for (int r = 0; r < 4; ++r) { m_st[r] = -1e30f; l_st[r] = 0.f; }
#pragma unroll
    for (int f = 0; f < 4; ++f) acc[f] = (f32x4){0.f, 0.f, 0.f, 0.f};

    int qg = qt * 64 + w * 16 + 4 * lr;

    // staging lambda: 4 gl16 per thread per tile (K + V, 2 chunks each)
    auto stage = [&](int buf, int kt) {
        int t0 = kt * 64;
#pragma unroll
        for (int j = 0; j < 2; ++j) {
            int idx = j * 256 + tid;
            int row = idx >> 3, ch = idx & 7;
            int sch = ch ^ (row & 7);
            gl16(Kp + (size_t)(t0 + row) * D_ + sch * 8, &Ks[buf][idx * 8]);
            gl16(Vp + (size_t)row * T_ + t0 + sch * 8, &Vs[buf][idx * 8]);
        }
    };

    stage(0, 0);
    asm volatile("s_waitcnt vmcnt(0)" ::: "memory");
    __builtin_amdgcn_s_barrier();

    for (int kt = 0; kt <= qt; ++kt) {
        int cur = kt & 1;
        if (kt < qt) stage(cur ^ 1, kt + 1);  // in flight during this tile's compute
        int t0 = kt * 64;

        // S = Q K^T
        f32x4 s[4];
        __builtin_amdgcn_s_setprio(1);
#pragma unroll
        for (int f = 0; f < 4; ++f) {
            s[f] = (f32x4){0.f, 0.f, 0.f, 0.f};
            int row = 16 * f + lc;
#pragma unroll
            for (int kk = 0; kk < 2; ++kk) {
                bf16x8 kf = *(const bf16x8*)&Ks[cur][row * 64 + (((lr + 4 * kk) ^ (row & 7)) * 8)];
                s[f] = mfma16(kk ? qf1 : qf0, kf, s[f]);
            }
        }
        __builtin_amdgcn_s_setprio(0);

        // scale (exp2 domain) + causal mask (diagonal tile only) + row max
        float tmax[4] = {-1e30f, -1e30f, -1e30f, -1e30f};
        if (kt == qt) {
#pragma unroll
            for (int f = 0; f < 4; ++f) {
                int kcol = t0 + 16 * f + lc;
#pragma unroll
                for (int r = 0; r < 4; ++r) {
                    float v = s[f][r] * SCALE_L2E;
                    v = (kcol > qg + r) ? -1e30f : v;
                    s[f][r] = v;
                    tmax[r] = fmaxf(tmax[r], v);
                }
            }
        } else {
#pragma unroll
            for (int f = 0; f < 4; ++f)
#pragma unroll
                for (int r = 0; r < 4; ++r) {
                    float v = s[f][r] * SCALE_L2E;
                    s[f][r] = v;
                    tmax[r] = fmaxf(tmax[r], v);
                }
        }
#pragma unroll
        for (int off = 1; off < 16; off <<= 1)
#pragma unroll
            for (int r = 0; r < 4; ++r)
                tmax[r] = fmaxf(tmax[r], __shfl_xor(tmax[r], off, 64));

        float alpha[4], psum[4];
#pragma unroll
        for (int r = 0; r < 4; ++r) {
            float mn = fmaxf(m_st[r], tmax[r]);
            alpha[r] = exp2f(m_st[r] - mn);
            m_st[r] = mn;
            psum[r] = 0.f;
        }
#pragma unroll
        for (int f = 0; f < 4; ++f)
#pragma unroll
            for (int r = 0; r < 4; ++r) {
                float p = exp2f(s[f][r] - m_st[r]);
                s[f][r] = p;
                psum[r] += p;
            }
#pragma unroll
        for (int off = 1; off < 16; off <<= 1)
#pragma unroll
            for (int r = 0; r < 4; ++r) psum[r] += __shfl_xor(psum[r], off, 64);
#pragma unroll
        for (int r = 0; r < 4; ++r) l_st[r] = l_st[r] * alpha[r] + psum[r];
#pragma unroll
        for (int f = 0; f < 4; ++f)
#pragma unroll
            for (int r = 0; r < 4; ++r) acc[f][r] *= alpha[r];

        // P -> per-wave LDS (swizzled), then PV
#pragma unroll
        for (int f = 0; f < 4; ++f)
#pragma unroll
            for (int r = 0; r < 4; ++r) {
                int prow = 4 * lr + r, pcol = 16 * f + lc;
                Ps[w][prow * 64 + (((pcol >> 3) ^ (prow & 7)) * 8) + (pcol & 7)] = f2bf(s[f][r]);
            }
        __builtin_amdgcn_s_setprio(1);
#pragma unroll
        for (int kk = 0; kk < 2; ++kk) {
            bf16x8 pf = *(const bf16x8*)&Ps[w][lc * 64 + (((lr + 4 * kk) ^ (lc & 7)) * 8)];
#pragma unroll
            for (int f = 0; f < 4; ++f) {
                int vrow = 16 * f + lc;
                bf16x8 vfr = *(const bf16x8*)&Vs[cur][vrow * 64 + (((lr + 4 * kk) ^ (vrow & 7)) * 8)];
                acc[f] = mfma16(pf, vfr, acc[f]);
            }
        }
        __builtin_amdgcn_s_setprio(0);

        // single barrier per tile: next-tile stage writes are complete (vmcnt 0)
        // and all waves are done reading buf[cur] before it gets overwritten next iter
        asm volatile("s_waitcnt vmcnt(0)" ::: "memory");
        __builtin_amdgcn_s_barrier();
    }

#pragma unroll
    for (int r = 0; r < 4; ++r) l_st[r] = 1.f / l_st[r];
#pragma unroll
    for (int f = 0; f < 4; ++f)
#pragma unroll
        for (int r = 0; r < 4; ++r) {
            int t = qt * 64 + w * 16 + 4 * lr + r;
            attnb[((size_t)(b * T_ + t)) * 1024 + h * 64 + 16 * f + lc] = f2bf(acc[f][r] * l_st[r]);
        }
}

extern "C" void kernel_launch(void* const* d_in, const int* in_sizes, int n_in,
                              void* d_out, int out_size, void* d_ws, size_t ws_size,
                              hipStream_t stream) {
    const float* hs     = (const float*)d_in[0];
    const float* cosp   = (const float*)d_in[1];
    const float* sinp   = (const float*)d_in[2];
    const float* qkv_w  = (const float*)d_in[3];
    const float* qkv_b  = (const float*)d_in[4];
    const float* proj_w = (const float*)d_in[5];
    const float* proj_b = (const float*)d_in[6];
    float* out = (float*)d_out;

    const int M = B_ * T_;            // 4096
    ushort_t* Xb     = (ushort_t*)d_ws;
    ushort_t* Wqkvb  = Xb + (size_t)M * C_;
    ushort_t* Wprojb = Wqkvb + (size_t)3072 * C_;
    ushort_t* QKV    = Wprojb + (size_t)C_ * C_;
    ushort_t* Qr     = QKV + (size_t)M * 3072;
    ushort_t* Kr     = Qr + (size_t)B_ * H_ * T_ * D_;
    ushort_t* Vt     = Kr + (size_t)B_ * H_ * T_ * D_;
    ushort_t* attnb  = Vt + (size_t)B_ * H_ * T_ * D_;

    cvt_kernel<<<1024, 256, 0, stream>>>(hs, Xb, M * C_);
    cvt_kernel<<<1024, 256, 0, stream>>>(qkv_w, Wqkvb, 3072 * C_);
    cvt_kernel<<<256, 256, 0, stream>>>(proj_w, Wprojb, C_ * C_);

    gemm_bt<1><<<dim3(3072 / 128, M / 128), 256, 0, stream>>>(
        Xb, Wqkvb, qkv_b, QKV, nullptr, M, 3072, C_);

    rope_scatter<<<B_ * H_ * (T_ / 64), 256, 0, stream>>>(QKV, cosp, sinp, Qr, Kr, Vt);

    attn_kernel<<<B_ * H_ * (T_ / 64), 256, 0, stream>>>(Qr, Kr, Vt, attnb);

    gemm_bt<0><<<dim3(1024 / 128, M / 128), 256, 0, stream>>>(
        attnb, Wprojb, proj_b, nullptr, out, M, C_, C_);
}